// Round 6
// baseline (199.016 us; speedup 1.0000x reference)
//
#include <hip/hip_runtime.h>
#include <cstdint>
#include <cstddef>

// SLAYER SRM-alpha constants, rounded-to-nearest f32 from double
#define THETA_F 10.0f
#define DS_C 0.9048374180359595731642491f   // exp(-0.1)
#define DR_C 0.3678794411714423215955238f   // exp(-1.0)
#define CS_C 0.2718281828459045235360287f   // e/10
#define CR_C -54.3656365691809047072057f    // -2*10*e
#define P100_C 4.5399929762484854e-05f      // ds^100 = e^-10
#define QC100_C 4.1079555325e-03f           // 100 * ds^101 = 100*e^-10.1

typedef unsigned int       u32;
typedef unsigned long long u64;
typedef unsigned short     u16;

// ws layout (exactly 8,192,000 bytes = 64*512*2000 bits):
//   w32 region : u32 [64][62][512]  bits for t in [tb*32, tb*32+32), bit j = t%32
//   tail region: u16 [64][512] at byte offset 64*62*512*4 = 8,126,464, bits t in [1984,2000)
#define W32_WORDS_PER_B  (62 * 512)
#define TAIL_BYTE_OFF    (64 * 62 * 512 * 4)

// ---------------------------------------------------------------------------
// K1: layer-1 fc (K=4, binary inputs -> 16-entry LDS table) + psp_spike.
// Unchanged from R5 (bit-exact path; 256 blocks x 128 threads, 1 wave/SIMD).
// ---------------------------------------------------------------------------
__global__ __launch_bounds__(128) void k1_layer1(
    const float* __restrict__ inp,                 // [64][4][2000]
    const float* __restrict__ W1,                  // [512][4]
    u32* __restrict__ w32, u16* __restrict__ tail16)
{
    __shared__ float table[16 * 128];
    __shared__ alignas(8) unsigned char codes[2048];

    const int tid = threadIdx.x;                   // 0..127
    const int b   = blockIdx.x >> 2;               // 0..63
    const int h   = ((blockIdx.x & 3) << 7) + tid; // 0..511

    const float w0 = W1[h * 4 + 0];
    const float w1 = W1[h * 4 + 1];
    const float w2 = W1[h * 4 + 2];
    const float w3 = W1[h * 4 + 3];
    for (int c = 0; c < 16; ++c) {
        float v = __fmul_rn(w0, (c & 1) ? 1.0f : 0.0f);
        v = __fadd_rn(v, __fmul_rn(w1, (c & 2) ? 1.0f : 0.0f));
        v = __fadd_rn(v, __fmul_rn(w2, (c & 4) ? 1.0f : 0.0f));
        v = __fadd_rn(v, __fmul_rn(w3, (c & 8) ? 1.0f : 0.0f));
        table[c * 128 + tid] = v;
    }
    for (int t = tid; t < 2000; t += 128) {
        const float v0 = inp[(b * 4 + 0) * 2000 + t];
        const float v1 = inp[(b * 4 + 1) * 2000 + t];
        const float v2 = inp[(b * 4 + 2) * 2000 + t];
        const float v3 = inp[(b * 4 + 3) * 2000 + t];
        codes[t] = (unsigned char)((int)(v0 != 0.0f) | ((int)(v1 != 0.0f) << 1) |
                                   ((int)(v2 != 0.0f) << 2) | ((int)(v3 != 0.0f) << 3));
    }
    if (tid < 48) codes[2000 + tid] = 0;   // pad
    __syncthreads();

#define ISSUE(CW, BUF) do {                                                   \
        const u32 lo_ = (u32)(CW), hi_ = (u32)((CW) >> 32);                   \
        BUF[0] = table[((lo_      ) & 15) * 128 + tid];                       \
        BUF[1] = table[((lo_ >>  8) & 15) * 128 + tid];                       \
        BUF[2] = table[((lo_ >> 16) & 15) * 128 + tid];                       \
        BUF[3] = table[((lo_ >> 24) & 15) * 128 + tid];                       \
        BUF[4] = table[((hi_      ) & 15) * 128 + tid];                       \
        BUF[5] = table[((hi_ >>  8) & 15) * 128 + tid];                       \
        BUF[6] = table[((hi_ >> 16) & 15) * 128 + tid];                       \
        BUF[7] = table[((hi_ >> 24) & 15) * 128 + tid];                       \
    } while (0)

#define STEP(AV, BITPOS) do {                                                 \
        const float u_ = __fadd_rn(__fmul_rn(CS_C, ys), __fmul_rn(CR_C, yr)); \
        const bool sp_ = (u_ >= THETA_F);                                     \
        xs = __fadd_rn(__fmul_rn(DS_C, xs), (AV));                            \
        ys = __fmul_rn(DS_C, __fadd_rn(ys, xs));                              \
        const float A_ = __fmul_rn(DR_C, xr);                                 \
        xr = sp_ ? __fadd_rn(A_, 1.0f) : A_;                                  \
        yr = __fmul_rn(DR_C, __fadd_rn(yr, xr));                              \
        bits = sp_ ? (bits | (1u << (BITPOS))) : bits;                        \
    } while (0)

#define STEP8(BUF, J0) do {                                                   \
        _Pragma("unroll")                                                     \
        for (int j_ = 0; j_ < 8; ++j_) STEP(BUF[j_], (J0) + j_);              \
    } while (0)

    float xs = 0.0f, ys = 0.0f, xr = 0.0f, yr = 0.0f;
    u32 bits = 0;
    u32* pw = w32 + (size_t)b * W32_WORDS_PER_B + h;

    float bA[8], bB[8];
    u64 cw = *reinterpret_cast<const u64*>(codes);
    ISSUE(cw, bA);
    u64 c1 = *reinterpret_cast<const u64*>(codes + 8);
    u64 c2 = *reinterpret_cast<const u64*>(codes + 16);
    u64 c3 = *reinterpret_cast<const u64*>(codes + 24);
    u64 c4 = *reinterpret_cast<const u64*>(codes + 32);

    for (int t0 = 0; t0 < 1984; t0 += 32) {
        ISSUE(c1, bB);
        const u64 n1 = *reinterpret_cast<const u64*>(codes + t0 + 40);
        const u64 n2 = *reinterpret_cast<const u64*>(codes + t0 + 48);
        const u64 n3 = *reinterpret_cast<const u64*>(codes + t0 + 56);
        const u64 n4 = *reinterpret_cast<const u64*>(codes + t0 + 64);
        STEP8(bA, 0);
        ISSUE(c2, bA);
        STEP8(bB, 8);
        ISSUE(c3, bB);
        STEP8(bA, 16);
        ISSUE(c4, bA);
        STEP8(bB, 24);
        *pw = bits; pw += 512; bits = 0;
        c1 = n1; c2 = n2; c3 = n3; c4 = n4;
    }
    ISSUE(c1, bB);
    STEP8(bA, 0);
    STEP8(bB, 8);
    tail16[b * 512 + h] = (u16)bits;

#undef STEP8
#undef STEP
#undef ISSUE
}

// ---------------------------------------------------------------------------
// K2: a2[b,o,t] = ascending-h sum of W2[o,h]*s1[b,h,t] (unchanged from R5).
// ---------------------------------------------------------------------------
__global__ __launch_bounds__(256) void k2_fc2(
    const u32* __restrict__ w32, const u16* __restrict__ tail16,
    const float* __restrict__ W2,                  // [2][512]
    float* __restrict__ a2)                        // [128][2000]
{
    __shared__ float w2s[1024];
    __shared__ u32 stage[4096];                    // [local tb 0..7][h 0..511]

    const int tid = threadIdx.x;
    const int b  = blockIdx.x >> 3;
    const int it = blockIdx.x & 7;

    for (int j = tid; j < 1024; j += 256) w2s[j] = W2[j];
    #pragma unroll
    for (int k = 0; k < 16; ++k) {
        const int l = tid + (k << 8);              // 0..4095
        const int gtb = (it << 3) + (l >> 9);
        u32 v = 0;
        if (gtb < 62)       v = w32[((size_t)b * 62 + gtb) * 512 + (l & 511)];
        else if (gtb == 62) v = (u32)tail16[b * 512 + (l & 511)];
        stage[l] = v;
    }
    __syncthreads();

    const int t = (it << 8) + tid;
    if (t < 2000) {
        const u32* srow = stage + ((tid >> 5) << 9);
        const int sh = tid & 31;
        float acc0 = 0.0f, acc1 = 0.0f;
        #pragma unroll 8
        for (int hh = 0; hh < 512; ++hh) {
            const bool on = (srow[hh] >> sh) & 1u;
            acc0 = __fadd_rn(acc0, on ? w2s[hh] : 0.0f);
            acc1 = __fadd_rn(acc1, on ? w2s[512 + hh] : 0.0f);
        }
        a2[(size_t)(b * 2 + 0) * 2000 + t] = acc0;
        a2[(size_t)(b * 2 + 1) * 2000 + t] = acc1;
    }
}

// ---------------------------------------------------------------------------
// K3a: layer-2 PSP (linear alpha filter of a2, NO spike feedback) computed
// chunk-parallel, in place over d_out rows: row[t] := u_pre(t) = cs*ys2(t-1).
// 128 chains x 20 chunks of 100 steps. Per block: 8 chains x 20 chunks = 160
// threads. Stage 1: zero-state filter (emit z, save end-state). Stage 2:
// 20-step per-chain prefix with closed-form M^100 ([[p,0],[q,p]], p=ds^100,
// q=100*ds^101). Stage 3: homogeneous correction z += cs*y_h(j).
// Reassociation error ~1e-5 << empirically-established layer-2 threshold
// margins (~0.03): no spike flips.
// ---------------------------------------------------------------------------
__global__ __launch_bounds__(160) void k3a_psp2(float* __restrict__ io)
{
    __shared__ float ex[8][20], ey[8][20], sx[8][20], sy[8][20];

    const int tid = threadIdx.x;                   // 0..159
    const int lc  = tid / 20;                      // local chain 0..7
    const int ck  = tid - lc * 20;                 // chunk 0..19
    const int chain = blockIdx.x * 8 + lc;         // 0..127
    float* seg = io + (size_t)chain * 2000 + ck * 100;

    // stage 1: zero-state response over this chunk, in place
    float X = 0.0f, Y = 0.0f;
    for (int g = 0; g < 25; ++g) {
        float4 q = *reinterpret_cast<const float4*>(seg + 4 * g);
        float z;
        z = __fmul_rn(CS_C, Y); X = __fmaf_rn(DS_C, X, q.x);
        Y = __fmul_rn(DS_C, __fadd_rn(Y, X)); q.x = z;
        z = __fmul_rn(CS_C, Y); X = __fmaf_rn(DS_C, X, q.y);
        Y = __fmul_rn(DS_C, __fadd_rn(Y, X)); q.y = z;
        z = __fmul_rn(CS_C, Y); X = __fmaf_rn(DS_C, X, q.z);
        Y = __fmul_rn(DS_C, __fadd_rn(Y, X)); q.z = z;
        z = __fmul_rn(CS_C, Y); X = __fmaf_rn(DS_C, X, q.w);
        Y = __fmul_rn(DS_C, __fadd_rn(Y, X)); q.w = z;
        *reinterpret_cast<float4*>(seg + 4 * g) = q;
    }
    ex[lc][ck] = X; ey[lc][ck] = Y;
    __syncthreads();

    // stage 2: serial prefix over 20 chunks (8 threads, one per local chain)
    if (tid < 8) {
        float x = 0.0f, y = 0.0f;
        for (int c = 0; c < 20; ++c) {
            sx[tid][c] = x; sy[tid][c] = y;
            const float xn = __fmaf_rn(P100_C, x, ex[tid][c]);
            const float yn = __fadd_rn(
                __fmaf_rn(QC100_C, x, __fmul_rn(P100_C, y)), ey[tid][c]);
            x = xn; y = yn;
        }
    }
    __syncthreads();

    // stage 3: homogeneous correction  z(t0+j) += cs * y_h(j)
    float xh = sx[lc][ck], yh = sy[lc][ck];
    if (ck != 0) {                                 // chunk 0: correction == 0
        for (int g = 0; g < 25; ++g) {
            float4 q = *reinterpret_cast<const float4*>(seg + 4 * g);
            q.x = __fmaf_rn(CS_C, yh, q.x);
            xh = __fmul_rn(DS_C, xh); yh = __fmul_rn(DS_C, __fadd_rn(yh, xh));
            q.y = __fmaf_rn(CS_C, yh, q.y);
            xh = __fmul_rn(DS_C, xh); yh = __fmul_rn(DS_C, __fadd_rn(yh, xh));
            q.z = __fmaf_rn(CS_C, yh, q.z);
            xh = __fmul_rn(DS_C, xh); yh = __fmul_rn(DS_C, __fadd_rn(yh, xh));
            q.w = __fmaf_rn(CS_C, yh, q.w);
            xh = __fmul_rn(DS_C, xh); yh = __fmul_rn(DS_C, __fadd_rn(yh, xh));
            *reinterpret_cast<float4*>(seg + 4 * g) = q;
        }
    }
}

// ---------------------------------------------------------------------------
// K3d: layer-2 spike generation (refractory feedback) + final psp readout.
// Membrane u(t) = row[t] (= cs*ys2(t-1), precomputed) + cr*yr2(t-1). Serial
// per chain, 128 chains; refractory + readout in exact reference op order.
// 8 named float4 buffers, full 32-step unroll. grid 2 x block 64.
// ---------------------------------------------------------------------------
__global__ __launch_bounds__(64) void k3d_spike(
    const float* __restrict__ rin, float* __restrict__ rout)
{
    const int idx = blockIdx.x * 64 + threadIdx.x; // row = b*2+o, 0..127
    const float* rowi = rin  + (size_t)idx * 2000;
    float*       rowo = rout + (size_t)idx * 2000;

    float xr2 = 0.0f, yr2 = 0.0f;
    float xs3 = 0.0f, ys3 = 0.0f;

    // xr2,xs3 >= 0 so cndmask(B+1,B) == B+s bitwise
#define K3STEP(UV, POUT) do {                                                 \
        const float u_ = __fadd_rn((UV), __fmul_rn(CR_C, yr2));               \
        const bool sp_ = (u_ >= THETA_F);                                     \
        POUT = __fmul_rn(CS_C, ys3);      /* readout BEFORE consuming s2[t] */\
        const float A_ = __fmul_rn(DR_C, xr2);                                \
        xr2 = sp_ ? __fadd_rn(A_, 1.0f) : A_;                                 \
        yr2 = __fmul_rn(DR_C, __fadd_rn(yr2, xr2));                           \
        const float B_ = __fmul_rn(DS_C, xs3);                                \
        xs3 = sp_ ? __fadd_rn(B_, 1.0f) : B_;                                 \
        ys3 = __fmul_rn(DS_C, __fadd_rn(ys3, xs3));                           \
    } while (0)

#define QUAD(BK, OFF) do {                                                    \
        float p0_, p1_, p2_, p3_;                                             \
        K3STEP(BK.x, p0_); K3STEP(BK.y, p1_);                                 \
        K3STEP(BK.z, p2_); K3STEP(BK.w, p3_);                                 \
        *reinterpret_cast<float4*>(rowo + t0 + (OFF)) =                       \
            make_float4(p0_, p1_, p2_, p3_);                                  \
        const int tn_ = t0 + 32 + (OFF);                                      \
        BK = *reinterpret_cast<const float4*>(rowi + ((tn_ < 2000) ? tn_ : 1984)); \
    } while (0)

#define TAILQUAD(BK, TPOS) do {                                               \
        float p0_, p1_, p2_, p3_;                                             \
        K3STEP(BK.x, p0_); K3STEP(BK.y, p1_);                                 \
        K3STEP(BK.z, p2_); K3STEP(BK.w, p3_);                                 \
        *reinterpret_cast<float4*>(rowo + (TPOS)) =                           \
            make_float4(p0_, p1_, p2_, p3_);                                  \
    } while (0)

    float4 b0 = *reinterpret_cast<const float4*>(rowi + 0);
    float4 b1 = *reinterpret_cast<const float4*>(rowi + 4);
    float4 b2 = *reinterpret_cast<const float4*>(rowi + 8);
    float4 b3 = *reinterpret_cast<const float4*>(rowi + 12);
    float4 b4 = *reinterpret_cast<const float4*>(rowi + 16);
    float4 b5 = *reinterpret_cast<const float4*>(rowi + 20);
    float4 b6 = *reinterpret_cast<const float4*>(rowi + 24);
    float4 b7 = *reinterpret_cast<const float4*>(rowi + 28);

    for (int t0 = 0; t0 < 1984; t0 += 32) {
        QUAD(b0, 0);  QUAD(b1, 4);  QUAD(b2, 8);  QUAD(b3, 12);
        QUAD(b4, 16); QUAD(b5, 20); QUAD(b6, 24); QUAD(b7, 28);
    }
    TAILQUAD(b0, 1984); TAILQUAD(b1, 1988);
    TAILQUAD(b2, 1992); TAILQUAD(b3, 1996);

#undef TAILQUAD
#undef QUAD
#undef K3STEP
}

extern "C" void kernel_launch(void* const* d_in, const int* in_sizes, int n_in,
                              void* d_out, int out_size, void* d_ws, size_t ws_size,
                              hipStream_t stream)
{
    const float* inp = (const float*)d_in[0];  // [64][4][2000]
    const float* W1  = (const float*)d_in[1];  // [512][4]
    const float* W2  = (const float*)d_in[2];  // [2][512]
    float* out = (float*)d_out;                // [64][2][2000]

    u32* w32    = (u32*)d_ws;
    u16* tail16 = (u16*)((char*)d_ws + TAIL_BYTE_OFF);

    k1_layer1<<<dim3(256), dim3(128), 0, stream>>>(inp, W1, w32, tail16);
    k2_fc2<<<dim3(512), dim3(256), 0, stream>>>(w32, tail16, W2, out);
    k3a_psp2<<<dim3(16), dim3(160), 0, stream>>>(out);
    k3d_spike<<<dim3(2), dim3(64), 0, stream>>>(out, out);
}

// Round 7
// 155.412 us; speedup vs baseline: 1.2806x; 1.2806x over previous
//
#include <hip/hip_runtime.h>
#include <cstdint>
#include <cstddef>

// SLAYER SRM-alpha constants, rounded-to-nearest f32 from double
#define THETA_F 10.0f
#define DS_C 0.9048374180359595731642491f   // exp(-0.1)
#define DR_C 0.3678794411714423215955238f   // exp(-1.0)
#define CS_C 0.2718281828459045235360287f   // e/10
#define CR_C -54.3656365691809047072057f    // -2*10*e
#define P100_C 4.5399929762484854e-05f      // ds^100 = e^-10
#define QC100_C 4.1079555325e-03f           // 100 * ds^101 = 100*e^-10.1

typedef unsigned int       u32;
typedef unsigned long long u64;
typedef unsigned short     u16;

// ws layout (>= 8,192,000 bytes):
//   w32 region : u32 [64][62][512]  layer-1 spike bits, t in [tb*32,tb*32+32)
//   tail region: u16 [64][512] at byte offset 8,126,464, bits t in [1984,2000)
//   s2 region  : float [128][2000] REUSES ws offset 0 (k2 consumed w32 before
//                k3d_par writes; k1 rewrites w32 every call -> deterministic)
#define W32_WORDS_PER_B  (62 * 512)
#define TAIL_BYTE_OFF    (64 * 62 * 512 * 4)

// ---------------------------------------------------------------------------
// K1: layer-1 fc (K=4, binary inputs -> 16-entry LDS table) + psp_spike.
// Unchanged from R5/R6 (bit-exact path; 256 blocks x 128 threads).
// ---------------------------------------------------------------------------
__global__ __launch_bounds__(128) void k1_layer1(
    const float* __restrict__ inp,                 // [64][4][2000]
    const float* __restrict__ W1,                  // [512][4]
    u32* __restrict__ w32, u16* __restrict__ tail16)
{
    __shared__ float table[16 * 128];
    __shared__ alignas(8) unsigned char codes[2048];

    const int tid = threadIdx.x;                   // 0..127
    const int b   = blockIdx.x >> 2;               // 0..63
    const int h   = ((blockIdx.x & 3) << 7) + tid; // 0..511

    const float w0 = W1[h * 4 + 0];
    const float w1 = W1[h * 4 + 1];
    const float w2 = W1[h * 4 + 2];
    const float w3 = W1[h * 4 + 3];
    for (int c = 0; c < 16; ++c) {
        float v = __fmul_rn(w0, (c & 1) ? 1.0f : 0.0f);
        v = __fadd_rn(v, __fmul_rn(w1, (c & 2) ? 1.0f : 0.0f));
        v = __fadd_rn(v, __fmul_rn(w2, (c & 4) ? 1.0f : 0.0f));
        v = __fadd_rn(v, __fmul_rn(w3, (c & 8) ? 1.0f : 0.0f));
        table[c * 128 + tid] = v;
    }
    for (int t = tid; t < 2000; t += 128) {
        const float v0 = inp[(b * 4 + 0) * 2000 + t];
        const float v1 = inp[(b * 4 + 1) * 2000 + t];
        const float v2 = inp[(b * 4 + 2) * 2000 + t];
        const float v3 = inp[(b * 4 + 3) * 2000 + t];
        codes[t] = (unsigned char)((int)(v0 != 0.0f) | ((int)(v1 != 0.0f) << 1) |
                                   ((int)(v2 != 0.0f) << 2) | ((int)(v3 != 0.0f) << 3));
    }
    if (tid < 48) codes[2000 + tid] = 0;   // pad
    __syncthreads();

#define ISSUE(CW, BUF) do {                                                   \
        const u32 lo_ = (u32)(CW), hi_ = (u32)((CW) >> 32);                   \
        BUF[0] = table[((lo_      ) & 15) * 128 + tid];                       \
        BUF[1] = table[((lo_ >>  8) & 15) * 128 + tid];                       \
        BUF[2] = table[((lo_ >> 16) & 15) * 128 + tid];                       \
        BUF[3] = table[((lo_ >> 24) & 15) * 128 + tid];                       \
        BUF[4] = table[((hi_      ) & 15) * 128 + tid];                       \
        BUF[5] = table[((hi_ >>  8) & 15) * 128 + tid];                       \
        BUF[6] = table[((hi_ >> 16) & 15) * 128 + tid];                       \
        BUF[7] = table[((hi_ >> 24) & 15) * 128 + tid];                       \
    } while (0)

#define STEP(AV, BITPOS) do {                                                 \
        const float u_ = __fadd_rn(__fmul_rn(CS_C, ys), __fmul_rn(CR_C, yr)); \
        const bool sp_ = (u_ >= THETA_F);                                     \
        xs = __fadd_rn(__fmul_rn(DS_C, xs), (AV));                            \
        ys = __fmul_rn(DS_C, __fadd_rn(ys, xs));                              \
        const float A_ = __fmul_rn(DR_C, xr);                                 \
        xr = sp_ ? __fadd_rn(A_, 1.0f) : A_;                                  \
        yr = __fmul_rn(DR_C, __fadd_rn(yr, xr));                              \
        bits = sp_ ? (bits | (1u << (BITPOS))) : bits;                        \
    } while (0)

#define STEP8(BUF, J0) do {                                                   \
        _Pragma("unroll")                                                     \
        for (int j_ = 0; j_ < 8; ++j_) STEP(BUF[j_], (J0) + j_);              \
    } while (0)

    float xs = 0.0f, ys = 0.0f, xr = 0.0f, yr = 0.0f;
    u32 bits = 0;
    u32* pw = w32 + (size_t)b * W32_WORDS_PER_B + h;

    float bA[8], bB[8];
    u64 cw = *reinterpret_cast<const u64*>(codes);
    ISSUE(cw, bA);
    u64 c1 = *reinterpret_cast<const u64*>(codes + 8);
    u64 c2 = *reinterpret_cast<const u64*>(codes + 16);
    u64 c3 = *reinterpret_cast<const u64*>(codes + 24);
    u64 c4 = *reinterpret_cast<const u64*>(codes + 32);

    for (int t0 = 0; t0 < 1984; t0 += 32) {
        ISSUE(c1, bB);
        const u64 n1 = *reinterpret_cast<const u64*>(codes + t0 + 40);
        const u64 n2 = *reinterpret_cast<const u64*>(codes + t0 + 48);
        const u64 n3 = *reinterpret_cast<const u64*>(codes + t0 + 56);
        const u64 n4 = *reinterpret_cast<const u64*>(codes + t0 + 64);
        STEP8(bA, 0);
        ISSUE(c2, bA);
        STEP8(bB, 8);
        ISSUE(c3, bB);
        STEP8(bA, 16);
        ISSUE(c4, bA);
        STEP8(bB, 24);
        *pw = bits; pw += 512; bits = 0;
        c1 = n1; c2 = n2; c3 = n3; c4 = n4;
    }
    ISSUE(c1, bB);
    STEP8(bA, 0);
    STEP8(bB, 8);
    tail16[b * 512 + h] = (u16)bits;

#undef STEP8
#undef STEP
#undef ISSUE
}

// ---------------------------------------------------------------------------
// K2: a2[b,o,t] = ascending-h sum of W2[o,h]*s1[b,h,t] (unchanged).
// ---------------------------------------------------------------------------
__global__ __launch_bounds__(256) void k2_fc2(
    const u32* __restrict__ w32, const u16* __restrict__ tail16,
    const float* __restrict__ W2,                  // [2][512]
    float* __restrict__ a2)                        // [128][2000]
{
    __shared__ float w2s[1024];
    __shared__ u32 stage[4096];                    // [local tb 0..7][h 0..511]

    const int tid = threadIdx.x;
    const int b  = blockIdx.x >> 3;
    const int it = blockIdx.x & 7;

    for (int j = tid; j < 1024; j += 256) w2s[j] = W2[j];
    #pragma unroll
    for (int k = 0; k < 16; ++k) {
        const int l = tid + (k << 8);              // 0..4095
        const int gtb = (it << 3) + (l >> 9);
        u32 v = 0;
        if (gtb < 62)       v = w32[((size_t)b * 62 + gtb) * 512 + (l & 511)];
        else if (gtb == 62) v = (u32)tail16[b * 512 + (l & 511)];
        stage[l] = v;
    }
    __syncthreads();

    const int t = (it << 8) + tid;
    if (t < 2000) {
        const u32* srow = stage + ((tid >> 5) << 9);
        const int sh = tid & 31;
        float acc0 = 0.0f, acc1 = 0.0f;
        #pragma unroll 8
        for (int hh = 0; hh < 512; ++hh) {
            const bool on = (srow[hh] >> sh) & 1u;
            acc0 = __fadd_rn(acc0, on ? w2s[hh] : 0.0f);
            acc1 = __fadd_rn(acc1, on ? w2s[512 + hh] : 0.0f);
        }
        a2[(size_t)(b * 2 + 0) * 2000 + t] = acc0;
        a2[(size_t)(b * 2 + 1) * 2000 + t] = acc1;
    }
}

// ---------------------------------------------------------------------------
// K3lin: chunk-parallel alpha filter (p(t)=cs*ys(t-1), ys driven by in[]).
// Used twice: (a) in=out=d_out -> layer-2 pre-membrane U from a2 (R6 k3a);
// (b) in=s2buf, out=d_out -> final psp readout from layer-2 spikes.
// 128 chains x 20 chunks of 100. Stage1 zero-state; stage2 M^100 prefix;
// stage3 homogeneous correction. Reassociation ~1e-5, validated R6.
// ---------------------------------------------------------------------------
__global__ __launch_bounds__(160) void k3lin(
    const float* __restrict__ in, float* __restrict__ out)
{
    __shared__ float ex[8][20], ey[8][20], sx[8][20], sy[8][20];

    const int tid = threadIdx.x;                   // 0..159
    const int lc  = tid / 20;                      // local chain 0..7
    const int ck  = tid - lc * 20;                 // chunk 0..19
    const int chain = blockIdx.x * 8 + lc;         // 0..127
    const float* segi = in  + (size_t)chain * 2000 + ck * 100;
    float*       sego = out + (size_t)chain * 2000 + ck * 100;

    // stage 1: zero-state response over this chunk
    float X = 0.0f, Y = 0.0f;
    for (int g = 0; g < 25; ++g) {
        float4 q = *reinterpret_cast<const float4*>(segi + 4 * g);
        float z;
        z = __fmul_rn(CS_C, Y); X = __fmaf_rn(DS_C, X, q.x);
        Y = __fmul_rn(DS_C, __fadd_rn(Y, X)); q.x = z;
        z = __fmul_rn(CS_C, Y); X = __fmaf_rn(DS_C, X, q.y);
        Y = __fmul_rn(DS_C, __fadd_rn(Y, X)); q.y = z;
        z = __fmul_rn(CS_C, Y); X = __fmaf_rn(DS_C, X, q.z);
        Y = __fmul_rn(DS_C, __fadd_rn(Y, X)); q.z = z;
        z = __fmul_rn(CS_C, Y); X = __fmaf_rn(DS_C, X, q.w);
        Y = __fmul_rn(DS_C, __fadd_rn(Y, X)); q.w = z;
        *reinterpret_cast<float4*>(sego + 4 * g) = q;
    }
    ex[lc][ck] = X; ey[lc][ck] = Y;
    __syncthreads();

    // stage 2: serial prefix over 20 chunks (one thread per local chain)
    if (tid < 8) {
        float x = 0.0f, y = 0.0f;
        for (int c = 0; c < 20; ++c) {
            sx[tid][c] = x; sy[tid][c] = y;
            const float xn = __fmaf_rn(P100_C, x, ex[tid][c]);
            const float yn = __fadd_rn(
                __fmaf_rn(QC100_C, x, __fmul_rn(P100_C, y)), ey[tid][c]);
            x = xn; y = yn;
        }
    }
    __syncthreads();

    // stage 3: homogeneous correction  out(t0+j) += cs * y_h(j)
    float xh = sx[lc][ck], yh = sy[lc][ck];
    if (ck != 0) {                                 // chunk 0: correction == 0
        for (int g = 0; g < 25; ++g) {
            float4 q = *reinterpret_cast<const float4*>(sego + 4 * g);
            q.x = __fmaf_rn(CS_C, yh, q.x);
            xh = __fmul_rn(DS_C, xh); yh = __fmul_rn(DS_C, __fadd_rn(yh, xh));
            q.y = __fmaf_rn(CS_C, yh, q.y);
            xh = __fmul_rn(DS_C, xh); yh = __fmul_rn(DS_C, __fadd_rn(yh, xh));
            q.z = __fmaf_rn(CS_C, yh, q.z);
            xh = __fmul_rn(DS_C, xh); yh = __fmul_rn(DS_C, __fadd_rn(yh, xh));
            q.w = __fmaf_rn(CS_C, yh, q.w);
            xh = __fmul_rn(DS_C, xh); yh = __fmul_rn(DS_C, __fadd_rn(yh, xh));
            *reinterpret_cast<float4*>(sego + 4 * g) = q;
        }
    }
}

// ---------------------------------------------------------------------------
// K3d_par: layer-2 spike generation, CHUNK-PARALLEL via refractory warm-up.
// Refractory state decays dr^k = e^-k per step, so starting 64 steps before
// the chunk with xr=yr=0 reproduces the true (xr,yr) at chunk start to
// ~e^-44 (sub-ulp in u; early warm-up spike errors decay e^-(64-k)).
// u(t) = U[t] + cr*yr (U = cs*ys2(t-1) precomputed by k3lin pass a) — exact
// per-step ops identical to the serial R6 k3d. 2560 threads: (chain, ck).
// Emits s2[chain][t] in {0.0,1.0}.
// ---------------------------------------------------------------------------
__global__ __launch_bounds__(256) void k3d_par(
    const float* __restrict__ U,                   // [128][2000] pre-membrane
    float* __restrict__ s2)                        // [128][2000] spikes out
{
    const int gid = blockIdx.x * 256 + threadIdx.x;   // 0..2559
    const int chain = gid / 20;                       // 0..127
    const int ck    = gid - chain * 20;               // 0..19
    const float* Urow = U + (size_t)chain * 2000;

    float xr2 = 0.0f, yr2 = 0.0f;

#define RSTEP(UV) do {                                                        \
        const float u_ = __fadd_rn((UV), __fmul_rn(CR_C, yr2));               \
        const bool sp_ = (u_ >= THETA_F);                                     \
        const float A_ = __fmul_rn(DR_C, xr2);                                \
        xr2 = sp_ ? __fadd_rn(A_, 1.0f) : A_;                                 \
        yr2 = __fmul_rn(DR_C, __fadd_rn(yr2, xr2));                           \
    } while (0)

#define ESTEP(UV, SOUT) do {                                                  \
        const float u_ = __fadd_rn((UV), __fmul_rn(CR_C, yr2));               \
        const bool sp_ = (u_ >= THETA_F);                                     \
        SOUT = sp_ ? 1.0f : 0.0f;                                             \
        const float A_ = __fmul_rn(DR_C, xr2);                                \
        xr2 = sp_ ? __fadd_rn(A_, 1.0f) : A_;                                 \
        yr2 = __fmul_rn(DR_C, __fadd_rn(yr2, xr2));                           \
    } while (0)

    if (ck != 0) {
        const float* wseg = Urow + ck * 100 - 64;     // 4-aligned (100ck-64)
        #pragma unroll
        for (int g = 0; g < 16; ++g) {
            const float4 q = *reinterpret_cast<const float4*>(wseg + 4 * g);
            RSTEP(q.x); RSTEP(q.y); RSTEP(q.z); RSTEP(q.w);
        }
    }

    const float* eseg = Urow + ck * 100;
    float* oseg = s2 + (size_t)chain * 2000 + ck * 100;
    #pragma unroll
    for (int g = 0; g < 25; ++g) {
        const float4 q = *reinterpret_cast<const float4*>(eseg + 4 * g);
        float4 o;
        ESTEP(q.x, o.x); ESTEP(q.y, o.y); ESTEP(q.z, o.z); ESTEP(q.w, o.w);
        *reinterpret_cast<float4*>(oseg + 4 * g) = o;
    }

#undef ESTEP
#undef RSTEP
}

extern "C" void kernel_launch(void* const* d_in, const int* in_sizes, int n_in,
                              void* d_out, int out_size, void* d_ws, size_t ws_size,
                              hipStream_t stream)
{
    const float* inp = (const float*)d_in[0];  // [64][4][2000]
    const float* W1  = (const float*)d_in[1];  // [512][4]
    const float* W2  = (const float*)d_in[2];  // [2][512]
    float* out = (float*)d_out;                // [64][2][2000]

    u32*   w32    = (u32*)d_ws;
    u16*   tail16 = (u16*)((char*)d_ws + TAIL_BYTE_OFF);
    float* s2buf  = (float*)d_ws;              // reuses w32 region after k2

    k1_layer1<<<dim3(256), dim3(128), 0, stream>>>(inp, W1, w32, tail16);
    k2_fc2<<<dim3(512), dim3(256), 0, stream>>>(w32, tail16, W2, out);
    k3lin<<<dim3(16), dim3(160), 0, stream>>>(out, out);      // a2 -> U
    k3d_par<<<dim3(10), dim3(256), 0, stream>>>(out, s2buf);  // U -> s2
    k3lin<<<dim3(16), dim3(160), 0, stream>>>(s2buf, out);    // s2 -> psp
}

// Round 10
// 137.502 us; speedup vs baseline: 1.4474x; 1.1302x over previous
//
#include <hip/hip_runtime.h>
#include <cstdint>
#include <cstddef>

// SLAYER SRM-alpha constants, rounded-to-nearest f32 from double
#define THETA_F 10.0f
#define DS_C 0.9048374180359595731642491f   // exp(-0.1)
#define DR_C 0.3678794411714423215955238f   // exp(-1.0)
#define CS_C 0.2718281828459045235360287f   // e/10
#define CR_C -54.3656365691809047072057f    // -2*10*e
#define P100_C 4.5399929762484854e-05f      // ds^100 = e^-10
#define QC100_C 4.1079555325e-03f           // 100 * ds^101

typedef unsigned int       u32;
typedef unsigned long long u64;
typedef unsigned short     u16;

// ws layout (8,192,000 bytes = 64*512*2000 bits):
//   w32 region : u32 [64][62][512]  layer-1 spike bits, t in [tb*32,tb*32+32)
//   tail region: u16 [64][512] at byte offset 8,126,464, bits t in [1984,2000)
#define W32_WORDS_PER_B  (62 * 512)
#define TAIL_BYTE_OFF    (64 * 62 * 512 * 4)

// ---------------------------------------------------------------------------
// K1: layer-1 fc + psp_spike — SERIAL, bit-exact (validated R5/R6/R7).
// Layer-1 admits no chunk-parallel split: R8 (prefix reassoc) and R9
// (bit-exact PSP snapshot + 48-step refractory warm-up) both flipped layer-1
// spikes; frequent firing keeps true (xr,yr) at O(1), warm-up reconstructs
// them only to ~ulp, and 65.7M decisions sample margins below that.
// 256 blocks x 128 threads, 1 wave/SIMD on 2 SIMDs/CU; ~103 cy/step
// (6-op loop-carried chain is the floor).
// ---------------------------------------------------------------------------
__global__ __launch_bounds__(128) void k1_layer1(
    const float* __restrict__ inp,                 // [64][4][2000]
    const float* __restrict__ W1,                  // [512][4]
    u32* __restrict__ w32, u16* __restrict__ tail16)
{
    __shared__ float table[16 * 128];
    __shared__ alignas(8) unsigned char codes[2048];

    const int tid = threadIdx.x;                   // 0..127
    const int b   = blockIdx.x >> 2;               // 0..63
    const int h   = ((blockIdx.x & 3) << 7) + tid; // 0..511

    const float w0 = W1[h * 4 + 0];
    const float w1 = W1[h * 4 + 1];
    const float w2 = W1[h * 4 + 2];
    const float w3 = W1[h * 4 + 3];
    // table[c] = ((w0*b0 + w1*b1) + w2*b2) + w3*b3, b_i in {0,1}: bit-identical
    // to the reference einsum contraction (established passing form).
    for (int c = 0; c < 16; ++c) {
        float v = __fmul_rn(w0, (c & 1) ? 1.0f : 0.0f);
        v = __fadd_rn(v, __fmul_rn(w1, (c & 2) ? 1.0f : 0.0f));
        v = __fadd_rn(v, __fmul_rn(w2, (c & 4) ? 1.0f : 0.0f));
        v = __fadd_rn(v, __fmul_rn(w3, (c & 8) ? 1.0f : 0.0f));
        table[c * 128 + tid] = v;
    }
    // stage all 2000 input codes (4-bit per t)
    for (int t = tid; t < 2000; t += 128) {
        const float v0 = inp[(b * 4 + 0) * 2000 + t];
        const float v1 = inp[(b * 4 + 1) * 2000 + t];
        const float v2 = inp[(b * 4 + 2) * 2000 + t];
        const float v3 = inp[(b * 4 + 3) * 2000 + t];
        codes[t] = (unsigned char)((int)(v0 != 0.0f) | ((int)(v1 != 0.0f) << 1) |
                                   ((int)(v2 != 0.0f) << 2) | ((int)(v3 != 0.0f) << 3));
    }
    if (tid < 48) codes[2000 + tid] = 0;   // pad
    __syncthreads();

#define ISSUE(CW, BUF) do {                                                   \
        const u32 lo_ = (u32)(CW), hi_ = (u32)((CW) >> 32);                   \
        BUF[0] = table[((lo_      ) & 15) * 128 + tid];                       \
        BUF[1] = table[((lo_ >>  8) & 15) * 128 + tid];                       \
        BUF[2] = table[((lo_ >> 16) & 15) * 128 + tid];                       \
        BUF[3] = table[((lo_ >> 24) & 15) * 128 + tid];                       \
        BUF[4] = table[((hi_      ) & 15) * 128 + tid];                       \
        BUF[5] = table[((hi_ >>  8) & 15) * 128 + tid];                       \
        BUF[6] = table[((hi_ >> 16) & 15) * 128 + tid];                       \
        BUF[7] = table[((hi_ >> 24) & 15) * 128 + tid];                       \
    } while (0)

    // exact reference rounding (TS=1 mults elided; (u>=theta) == ((u-theta)>=0);
    // xr >= 0 always so cndmask(A+1, A) == A + s bitwise)
#define STEP(AV, BITPOS) do {                                                 \
        const float u_ = __fadd_rn(__fmul_rn(CS_C, ys), __fmul_rn(CR_C, yr)); \
        const bool sp_ = (u_ >= THETA_F);                                     \
        xs = __fadd_rn(__fmul_rn(DS_C, xs), (AV));                            \
        ys = __fmul_rn(DS_C, __fadd_rn(ys, xs));                              \
        const float A_ = __fmul_rn(DR_C, xr);                                 \
        xr = sp_ ? __fadd_rn(A_, 1.0f) : A_;                                  \
        yr = __fmul_rn(DR_C, __fadd_rn(yr, xr));                              \
        bits = sp_ ? (bits | (1u << (BITPOS))) : bits;                        \
    } while (0)

#define STEP8(BUF, J0) do {                                                   \
        _Pragma("unroll")                                                     \
        for (int j_ = 0; j_ < 8; ++j_) STEP(BUF[j_], (J0) + j_);              \
    } while (0)

    float xs = 0.0f, ys = 0.0f, xr = 0.0f, yr = 0.0f;
    u32 bits = 0;
    u32* pw = w32 + (size_t)b * W32_WORDS_PER_B + h;

    float bA[8], bB[8];
    u64 cw = *reinterpret_cast<const u64*>(codes);
    ISSUE(cw, bA);
    u64 c1 = *reinterpret_cast<const u64*>(codes + 8);
    u64 c2 = *reinterpret_cast<const u64*>(codes + 16);
    u64 c3 = *reinterpret_cast<const u64*>(codes + 24);
    u64 c4 = *reinterpret_cast<const u64*>(codes + 32);

    for (int t0 = 0; t0 < 1984; t0 += 32) {
        ISSUE(c1, bB);
        const u64 n1 = *reinterpret_cast<const u64*>(codes + t0 + 40);
        const u64 n2 = *reinterpret_cast<const u64*>(codes + t0 + 48);
        const u64 n3 = *reinterpret_cast<const u64*>(codes + t0 + 56);
        const u64 n4 = *reinterpret_cast<const u64*>(codes + t0 + 64);
        STEP8(bA, 0);
        ISSUE(c2, bA);
        STEP8(bB, 8);
        ISSUE(c3, bB);
        STEP8(bA, 16);
        ISSUE(c4, bA);
        STEP8(bB, 24);
        *pw = bits; pw += 512; bits = 0;
        c1 = n1; c2 = n2; c3 = n3; c4 = n4;
    }
    // tail: bA holds t=1984..1991 (issued with c4 at t0=1952); c1 = codes[1992..2000)
    ISSUE(c1, bB);
    STEP8(bA, 0);
    STEP8(bB, 8);
    tail16[b * 512 + h] = (u16)bits;

#undef STEP8
#undef STEP
#undef ISSUE
}

// ---------------------------------------------------------------------------
// K2: a2[b,o,t] = ascending-h sum of W2[o,h]*s1[b,h,t] (unchanged, validated).
// ---------------------------------------------------------------------------
__global__ __launch_bounds__(256) void k2_fc2(
    const u32* __restrict__ w32, const u16* __restrict__ tail16,
    const float* __restrict__ W2,                  // [2][512]
    float* __restrict__ a2)                        // [128][2000]
{
    __shared__ float w2s[1024];
    __shared__ u32 stage[4096];                    // [local tb 0..7][h 0..511]

    const int tid = threadIdx.x;
    const int b  = blockIdx.x >> 3;
    const int it = blockIdx.x & 7;

    for (int j = tid; j < 1024; j += 256) w2s[j] = W2[j];
    #pragma unroll
    for (int k = 0; k < 16; ++k) {
        const int l = tid + (k << 8);              // 0..4095
        const int gtb = (it << 3) + (l >> 9);
        u32 v = 0;
        if (gtb < 62)       v = w32[((size_t)b * 62 + gtb) * 512 + (l & 511)];
        else if (gtb == 62) v = (u32)tail16[b * 512 + (l & 511)];
        stage[l] = v;
    }
    __syncthreads();

    const int t = (it << 8) + tid;
    if (t < 2000) {
        const u32* srow = stage + ((tid >> 5) << 9);
        const int sh = tid & 31;
        float acc0 = 0.0f, acc1 = 0.0f;
        #pragma unroll 8
        for (int hh = 0; hh < 512; ++hh) {
            const bool on = (srow[hh] >> sh) & 1u;
            acc0 = __fadd_rn(acc0, on ? w2s[hh] : 0.0f);
            acc1 = __fadd_rn(acc1, on ? w2s[512 + hh] : 0.0f);
        }
        a2[(size_t)(b * 2 + 0) * 2000 + t] = acc0;
        a2[(size_t)(b * 2 + 1) * 2000 + t] = acc1;
    }
}

// ---------------------------------------------------------------------------
// K3all: merged tail — arithmetic byte-identical to R7's validated
// k3lin (a2->U) + k3d_par (U->s2, 64-step refractory warm-up) + k3lin
// (s2->psp), with U and s2 staged in LDS instead of global (identical
// values; bytes->float for s2 is exact 0.0/1.0). 4 chains/block, 41.3 KB
// LDS. grid 32 x block 80 (4 chains x 20 chunks of 100).
// ---------------------------------------------------------------------------
__global__ __launch_bounds__(80) void k3all(
    const float* __restrict__ a2, float* __restrict__ out)
{
    __shared__ float U[4][2000];
    __shared__ unsigned char s2b[4][2000];
    __shared__ float ex[4][20], ey[4][20], px[4][20], py[4][20];

    const int tid = threadIdx.x;                   // 0..79
    const int lc  = tid / 20;                      // 0..3
    const int ck  = tid - lc * 20;                 // 0..19
    const int chain = blockIdx.x * 4 + lc;         // 0..127

    // ---- phase 0: a2 -> U (k3lin form, validated R6/R7) ----
    {
        const float* segi = a2 + (size_t)chain * 2000 + ck * 100;
        float* segU = &U[lc][ck * 100];
        float X = 0.0f, Y = 0.0f;
        for (int g = 0; g < 25; ++g) {
            float4 qv = *reinterpret_cast<const float4*>(segi + 4 * g);
            float z;
            z = __fmul_rn(CS_C, Y); X = __fmaf_rn(DS_C, X, qv.x);
            Y = __fmul_rn(DS_C, __fadd_rn(Y, X)); qv.x = z;
            z = __fmul_rn(CS_C, Y); X = __fmaf_rn(DS_C, X, qv.y);
            Y = __fmul_rn(DS_C, __fadd_rn(Y, X)); qv.y = z;
            z = __fmul_rn(CS_C, Y); X = __fmaf_rn(DS_C, X, qv.z);
            Y = __fmul_rn(DS_C, __fadd_rn(Y, X)); qv.z = z;
            z = __fmul_rn(CS_C, Y); X = __fmaf_rn(DS_C, X, qv.w);
            Y = __fmul_rn(DS_C, __fadd_rn(Y, X)); qv.w = z;
            *reinterpret_cast<float4*>(segU + 4 * g) = qv;
        }
        ex[lc][ck] = X; ey[lc][ck] = Y;
    }
    __syncthreads();
    if (tid < 4) {
        float x = 0.0f, y = 0.0f;
        for (int c = 0; c < 20; ++c) {
            px[tid][c] = x; py[tid][c] = y;
            const float xn = __fmaf_rn(P100_C, x, ex[tid][c]);
            const float yn = __fadd_rn(
                __fmaf_rn(QC100_C, x, __fmul_rn(P100_C, y)), ey[tid][c]);
            x = xn; y = yn;
        }
    }
    __syncthreads();
    {
        float xh = px[lc][ck], yh = py[lc][ck];
        float* segU = &U[lc][ck * 100];
        if (ck != 0) {
            for (int g = 0; g < 25; ++g) {
                float4 qv = *reinterpret_cast<const float4*>(segU + 4 * g);
                qv.x = __fmaf_rn(CS_C, yh, qv.x);
                xh = __fmul_rn(DS_C, xh); yh = __fmul_rn(DS_C, __fadd_rn(yh, xh));
                qv.y = __fmaf_rn(CS_C, yh, qv.y);
                xh = __fmul_rn(DS_C, xh); yh = __fmul_rn(DS_C, __fadd_rn(yh, xh));
                qv.z = __fmaf_rn(CS_C, yh, qv.z);
                xh = __fmul_rn(DS_C, xh); yh = __fmul_rn(DS_C, __fadd_rn(yh, xh));
                qv.w = __fmaf_rn(CS_C, yh, qv.w);
                xh = __fmul_rn(DS_C, xh); yh = __fmul_rn(DS_C, __fadd_rn(yh, xh));
                *reinterpret_cast<float4*>(segU + 4 * g) = qv;
            }
        }
    }
    __syncthreads();

    // ---- phase 1: U -> s2 bytes (k3d_par form, 64-step warm-up, valid. R7) ----
    {
        float xr2 = 0.0f, yr2 = 0.0f;
#define RSTEP(UV) do {                                                        \
        const float u_ = __fadd_rn((UV), __fmul_rn(CR_C, yr2));               \
        const bool sp_ = (u_ >= THETA_F);                                     \
        const float A_ = __fmul_rn(DR_C, xr2);                                \
        xr2 = sp_ ? __fadd_rn(A_, 1.0f) : A_;                                 \
        yr2 = __fmul_rn(DR_C, __fadd_rn(yr2, xr2));                           \
    } while (0)
        if (ck != 0) {
            const float* wseg = &U[lc][ck * 100 - 64];
            #pragma unroll
            for (int g = 0; g < 16; ++g) {
                const float4 qv = *reinterpret_cast<const float4*>(wseg + 4 * g);
                RSTEP(qv.x); RSTEP(qv.y); RSTEP(qv.z); RSTEP(qv.w);
            }
        }
        const float* eseg = &U[lc][ck * 100];
        unsigned char* ob = &s2b[lc][ck * 100];
        for (int g = 0; g < 25; ++g) {
            const float4 qv = *reinterpret_cast<const float4*>(eseg + 4 * g);
            const float uv[4] = {qv.x, qv.y, qv.z, qv.w};
            #pragma unroll
            for (int j = 0; j < 4; ++j) {
                const float u_ = __fadd_rn(uv[j], __fmul_rn(CR_C, yr2));
                const bool sp_ = (u_ >= THETA_F);
                ob[4 * g + j] = sp_ ? 1 : 0;
                const float A_ = __fmul_rn(DR_C, xr2);
                xr2 = sp_ ? __fadd_rn(A_, 1.0f) : A_;
                yr2 = __fmul_rn(DR_C, __fadd_rn(yr2, xr2));
            }
        }
#undef RSTEP
    }
    __syncthreads();

    // ---- phase 2: s2 -> out (final psp readout, validated R6/R7 form) ----
    float* sego = out + (size_t)chain * 2000 + ck * 100;
    {
        const unsigned char* si = &s2b[lc][ck * 100];
        float X = 0.0f, Y = 0.0f;
        for (int j = 0; j < 100; ++j) {
            const float a = (float)si[j];
            const float z = __fmul_rn(CS_C, Y);
            X = __fmaf_rn(DS_C, X, a);
            Y = __fmul_rn(DS_C, __fadd_rn(Y, X));
            sego[j] = z;
        }
        ex[lc][ck] = X; ey[lc][ck] = Y;
    }
    __syncthreads();
    if (tid < 4) {
        float x = 0.0f, y = 0.0f;
        for (int c = 0; c < 20; ++c) {
            px[tid][c] = x; py[tid][c] = y;
            const float xn = __fmaf_rn(P100_C, x, ex[tid][c]);
            const float yn = __fadd_rn(
                __fmaf_rn(QC100_C, x, __fmul_rn(P100_C, y)), ey[tid][c]);
            x = xn; y = yn;
        }
    }
    __syncthreads();
    {
        float xh = px[lc][ck], yh = py[lc][ck];
        if (ck != 0) {
            for (int j = 0; j < 100; ++j) {
                sego[j] = __fmaf_rn(CS_C, yh, sego[j]);
                xh = __fmul_rn(DS_C, xh);
                yh = __fmul_rn(DS_C, __fadd_rn(yh, xh));
            }
        }
    }
}

extern "C" void kernel_launch(void* const* d_in, const int* in_sizes, int n_in,
                              void* d_out, int out_size, void* d_ws, size_t ws_size,
                              hipStream_t stream)
{
    const float* inp = (const float*)d_in[0];  // [64][4][2000]
    const float* W1  = (const float*)d_in[1];  // [512][4]
    const float* W2  = (const float*)d_in[2];  // [2][512]
    float* out = (float*)d_out;                // [64][2][2000]

    u32* w32    = (u32*)d_ws;
    u16* tail16 = (u16*)((char*)d_ws + TAIL_BYTE_OFF);

    k1_layer1<<<dim3(256), dim3(128), 0, stream>>>(inp, W1, w32, tail16);
    k2_fc2<<<dim3(512), dim3(256), 0, stream>>>(w32, tail16, W2, out);
    k3all<<<dim3(32), dim3(80), 0, stream>>>(out, out);
}